// Round 4
// baseline (754.737 us; speedup 1.0000x reference)
//
#include <hip/hip_runtime.h>
#include <hip/hip_bf16.h>

// Problem constants
#define BB   4
#define SS   2048
#define HID_ 768
#define NH   12
#define HD_  64
#define MR   8192          // B*S
#define XELEMS 6291456     // 8192*768

typedef __attribute__((ext_vector_type(8))) short short8;
typedef __attribute__((ext_vector_type(4))) float floatx4;

__device__ __forceinline__ unsigned short f2bf(float f) {
  union { float f; unsigned int u; } x; x.f = f;
  unsigned int r = x.u + 0x7fffu + ((x.u >> 16) & 1u);  // RNE
  return (unsigned short)(r >> 16);
}

// round-half-up f32 -> bf16 (1 int add + shift; fine vs 0.106 tolerance)
__device__ __forceinline__ unsigned short f2bf_fast(float f) {
  return (unsigned short)((__builtin_bit_cast(unsigned int, f) + 0x8000u) >> 16);
}

// 16-lane (DPP row) rotate-reduce sum — VALU pipe, no LDS traffic
template <int CTRL>
__device__ __forceinline__ float dpp_ror(float x) {
  return __builtin_bit_cast(float, __builtin_amdgcn_update_dpp(
      0, __builtin_bit_cast(int, x), CTRL, 0xF, 0xF, true));
}
__device__ __forceinline__ float rowsum16(float x) {
  x += dpp_ror<0x128>(x);  // row_ror:8
  x += dpp_ror<0x124>(x);  // row_ror:4
  x += dpp_ror<0x122>(x);  // row_ror:2
  x += dpp_ror<0x121>(x);  // row_ror:1
  return x;
}

// async global -> LDS, 16 B per lane; lds base is wave-uniform, HW adds lane*16
__device__ __forceinline__ void gload_lds16(const unsigned short* g, unsigned short* l) {
  __builtin_amdgcn_global_load_lds(
      (const __attribute__((address_space(1))) unsigned int*)g,
      (__attribute__((address_space(3))) unsigned int*)l, 16, 0, 0);
}

// ---------------------------------------------------------------- cast fp32 -> bf16 (both streams)
struct CastArgs { const float* src[2]; unsigned short* dst[2]; };

__global__ __launch_bounds__(256)
void cast_kernel(CastArgs a) {
  const int z = blockIdx.y;
  int i = (blockIdx.x * 256 + threadIdx.x) * 4;
  float4 v = *(const float4*)(a.src[z] + i);
  ushort4 o;
  o.x = f2bf(v.x); o.y = f2bf(v.y); o.z = f2bf(v.z); o.w = f2bf(v.w);
  *(ushort4*)(a.dst[z] + i) = o;
}

// ---------------------------------------------------------------- weight transpose+cast
// in: W[k][n] fp32 (768x768), out: Wt[n][k] bf16
struct WArgs { const float* src[8]; unsigned short* dst[8]; };

__global__ __launch_bounds__(256)
void wcast_kernel(WArgs args) {
  __shared__ float tile[32][33];
  const int w = blockIdx.z;
  const float* __restrict__ src = args.src[w];
  unsigned short* __restrict__ dst = args.dst[w];
  const int n0 = blockIdx.x * 32, k0 = blockIdx.y * 32;
  const int tx = threadIdx.x & 31, ty = threadIdx.x >> 5;  // 32 x 8
  #pragma unroll
  for (int i = 0; i < 4; ++i)
    tile[ty + 8 * i][tx] = src[(size_t)(k0 + ty + 8 * i) * HID_ + n0 + tx];
  __syncthreads();
  #pragma unroll
  for (int i = 0; i < 4; ++i)
    dst[(size_t)(n0 + ty + 8 * i) * HID_ + k0 + tx] = f2bf(tile[tx][ty + 8 * i]);
}

// ---------------------------------------------------------------- GEMM: C = A[M,768] * Bt[N,768]^T
// 128x128 tile, 4 waves of 64x64, 16x16x32 bf16 MFMA, BK=32,
// double-buffered global_load_lds staging + fine vmcnt (no barrier drain).
// MODE 0: bf16 out; per-z tmode 0 = row-major [tok][hid], 2 = V-transposed [b,h,d,s]
// MODE 1: fp32 out = acc + bias + resid
struct GemmArgs {
  const unsigned short* A[6];
  const unsigned short* Bt[6];
  const float* bias[6];
  const float* resid[6];
  unsigned short* outb[6];
  float* outf[6];
  int tmode[6];
};

template <int MODE>
__global__ __launch_bounds__(256)
void gemm_kernel(GemmArgs args) {
  const int z = blockIdx.z;
  const unsigned short* __restrict__ A  = args.A[z];
  const unsigned short* __restrict__ Bt = args.Bt[z];
  const int m0 = blockIdx.x * 128;
  const int n0 = blockIdx.y * 128;

  __shared__ __align__(16) unsigned short a_sh[2][4096];  // 2 x 8 KB, pitch 32
  __shared__ __align__(16) unsigned short b_sh[2][4096];

  const int tid  = threadIdx.x;
  const int lane = tid & 63;
  const int wave = tid >> 6;
  const int wm = (wave & 1) * 64;
  const int wn = (wave >> 1) * 64;
  const int l15 = lane & 15;
  const int ko  = lane >> 4;     // 0..3

  floatx4 acc[4][4];
  #pragma unroll
  for (int mt = 0; mt < 4; ++mt)
    #pragma unroll
    for (int nt = 0; nt < 4; ++nt) {
      floatx4 zz = {0.f, 0.f, 0.f, 0.f};
      acc[mt][nt] = zz;
    }

  // staging: 8 chunks of 16 rows x 32 cols; wave handles chunks {2w, 2w+1}
  size_t aoff[2], boff[2];
  int dsto[2];
  #pragma unroll
  for (int j = 0; j < 2; ++j) {
    const int ch = wave * 2 + j;
    const int row = ch * 16 + (lane >> 2);
    const int col = (lane & 3) * 8;
    aoff[j] = (size_t)(m0 + row) * 768 + col;
    boff[j] = (size_t)(n0 + row) * 768 + col;
    dsto[j] = ch * 512;
  }

  // prologue: stage k0=0 into buf 0
  #pragma unroll
  for (int j = 0; j < 2; ++j) {
    gload_lds16(A  + aoff[j], &a_sh[0][0] + dsto[j]);
    gload_lds16(Bt + boff[j], &b_sh[0][0] + dsto[j]);
  }

  for (int k0 = 0; k0 < 768; k0 += 32) {
    const int cb = (k0 >> 5) & 1;
    if (k0 + 32 < 768) {
      #pragma unroll
      for (int j = 0; j < 2; ++j) {
        gload_lds16(A  + aoff[j] + k0 + 32, &a_sh[cb ^ 1][0] + dsto[j]);
        gload_lds16(Bt + boff[j] + k0 + 32, &b_sh[cb ^ 1][0] + dsto[j]);
      }
      asm volatile("s_waitcnt vmcnt(4)" ::: "memory");
    } else {
      asm volatile("s_waitcnt vmcnt(0)" ::: "memory");
    }
    __builtin_amdgcn_s_barrier();
    asm volatile("" ::: "memory");

    short8 af[4], bfr[4];
    #pragma unroll
    for (int t = 0; t < 4; ++t) {
      af[t]  = *(const short8*)(&a_sh[cb][0] + (wm + t * 16 + l15) * 32 + ko * 8);
      bfr[t] = *(const short8*)(&b_sh[cb][0] + (wn + t * 16 + l15) * 32 + ko * 8);
    }
    #pragma unroll
    for (int mt = 0; mt < 4; ++mt)
      #pragma unroll
      for (int nt = 0; nt < 4; ++nt)
        acc[mt][nt] = __builtin_amdgcn_mfma_f32_16x16x32_bf16(af[mt], bfr[nt], acc[mt][nt], 0, 0, 0);

    asm volatile("" ::: "memory");
    __builtin_amdgcn_s_barrier();   // all waves done reading cb before next staging into cb
  }

  // epilogue. C/D layout: row = (lane>>4)*4 + r, col = lane&15
  if (MODE == 0) {
    const float* __restrict__ bias = args.bias[z];
    unsigned short* __restrict__ out = args.outb[z];
    if (args.tmode[z] == 0) {
      #pragma unroll
      for (int mt = 0; mt < 4; ++mt) {
        const int gm = m0 + wm + mt * 16 + ko * 4;
        #pragma unroll
        for (int nt = 0; nt < 4; ++nt) {
          const int gn = n0 + wn + nt * 16 + l15;
          const float bv = bias[gn];
          #pragma unroll
          for (int r = 0; r < 4; ++r)
            out[(size_t)(gm + r) * 768 + gn] = f2bf(acc[mt][nt][r] + bv);
        }
      }
    } else {
      // V: write transposed [b][h][d][s]; r walks consecutive s -> ushort4 stores
      #pragma unroll
      for (int mt = 0; mt < 4; ++mt) {
        const int gm = m0 + wm + mt * 16 + ko * 4;
        const int bb_ = gm >> 11;
        const int s   = gm & 2047;
        #pragma unroll
        for (int nt = 0; nt < 4; ++nt) {
          const int gn = n0 + wn + nt * 16 + l15;
          const float bv = bias[gn];
          const int h = gn >> 6, d = gn & 63;
          ushort4 o4;
          o4.x = f2bf(acc[mt][nt][0] + bv);
          o4.y = f2bf(acc[mt][nt][1] + bv);
          o4.z = f2bf(acc[mt][nt][2] + bv);
          o4.w = f2bf(acc[mt][nt][3] + bv);
          *(ushort4*)(out + ((size_t)((bb_ * 12 + h) * 64 + d)) * 2048 + s) = o4;
        }
      }
    }
  } else {
    const float* __restrict__ bias  = args.bias[z];
    const float* __restrict__ resid = args.resid[z];
    float* __restrict__ out = args.outf[z];
    #pragma unroll
    for (int mt = 0; mt < 4; ++mt) {
      const int gm = m0 + wm + mt * 16 + ko * 4;
      #pragma unroll
      for (int nt = 0; nt < 4; ++nt) {
        const int gn = n0 + wn + nt * 16 + l15;
        const float bv = bias[gn];
        #pragma unroll
        for (int r = 0; r < 4; ++r)
          out[(size_t)(gm + r) * 768 + gn] = acc[mt][nt][r] + bv + resid[(size_t)(gm + r) * 768 + gn];
      }
    }
  }
}

// ---------------------------------------------------------------- flash attention
// grid: (S/256, H, B*2).  z = b*2 + w; ctx[w] uses Q from the OTHER stream.
// 64 q-rows PER WAVE (block Q-tile 256) -> half the per-work LDS fragment
// traffic vs 32 q/wave (K/V/P frags are duplicated per wave).  K-tile 64,
// processed in 32-key halves so the P scratch fits pitch 40.
// Double-buffered K/V staging via global_load_lds (XOR-swizzled), fine vmcnt.
// No max-tracking; per-row exp sums accumulate in registers, one DPP
// reduction in the epilogue.
struct AttnArgs {
  const unsigned short* q[2];
  const unsigned short* k[2];
  const unsigned short* vt[2];
  const float* mask[2];
  unsigned short* ctx[2];
};

__global__ __launch_bounds__(256, 3)
void attn_kernel(AttnArgs args) {
  const int z = blockIdx.z;
  const int b = z >> 1, w = z & 1;
  const int h = blockIdx.y;
  const int q0 = blockIdx.x * 256;

  const unsigned short* __restrict__ Q  = args.q[1 - w];  // ctx1 <- q2, ctx2 <- q1
  const unsigned short* __restrict__ K  = args.k[w];
  const unsigned short* __restrict__ Vt = args.vt[w] + ((size_t)(b * 12 + h)) * 64 * 2048;
  const float* __restrict__ mask = args.mask[w] + (size_t)b * SS;
  unsigned short* __restrict__ O = args.ctx[w];

  // per buf 8192 elems: K half-tiles [ks][64 key][32 d] at 0,
  // V half-tiles [ksh][64 d][32 key] at 4096. 8-elem blocks XOR-swizzled by row&3.
  __shared__ __align__(16) unsigned short kv_sh[2][8192];
  __shared__ __align__(16) unsigned short p_sh[4][64 * 40];  // 64 q x 32 keys (half), pitch 40

  const int tid  = threadIdx.x;
  const int lane = tid & 63;
  const int wave = tid >> 6;
  const int l15 = lane & 15;
  const int lq  = lane >> 4;   // 0..3
  const int sw8 = (lq ^ (l15 & 3)) * 8;  // swizzled block offset for frag reads

  // staging sources: waves 0,1 stage the two K d-halves; waves 2,3 the two V key-halves
  const unsigned short* gbase;
  int gadv;
  int goff[4];
  {
    const int rl = lane >> 2;                  // row_local 0..15
    const int jb = (lane & 3) ^ (rl & 3);      // swizzled 8-elem block
    if (wave < 2) {
      gbase = K + (size_t)(b * SS) * 768 + h * 64 + (wave & 1) * 32;
      gadv  = 64 * 768;
      #pragma unroll
      for (int j = 0; j < 4; ++j) goff[j] = (j * 16 + rl) * 768 + jb * 8;
    } else {
      gbase = Vt + (wave & 1) * 32;
      gadv  = 64;
      #pragma unroll
      for (int j = 0; j < 4; ++j) goff[j] = (j * 16 + rl) * 2048 + jb * 8;
    }
  }

  // Q fragments: rows q0 + wave*64 + mt*16 + l15, k = ks*32 + lq*8 + j
  short8 qf[4][2];
  #pragma unroll
  for (int mt = 0; mt < 4; ++mt) {
    const size_t qrow = (size_t)(b * SS + q0 + wave * 64 + mt * 16 + l15) * 768 + h * 64;
    qf[mt][0] = *(const short8*)(Q + qrow + lq * 8);
    qf[mt][1] = *(const short8*)(Q + qrow + 32 + lq * 8);
  }

  floatx4 oacc[4][4];
  #pragma unroll
  for (int mt = 0; mt < 4; ++mt)
    #pragma unroll
    for (int nt = 0; nt < 4; ++nt) { floatx4 zz = {0.f,0.f,0.f,0.f}; oacc[mt][nt] = zz; }
  float lad[4][4];
  #pragma unroll
  for (int mt = 0; mt < 4; ++mt)
    #pragma unroll
    for (int r = 0; r < 4; ++r) lad[mt][r] = 0.f;

  const float SCL2 = 0.125f * 1.4426950408889634f;  // /sqrt(64) * log2(e)
  const float L2E  = 1.4426950408889634f;

  // prefetch tile 0: mask then K/V
  float mk_cur[4], mk_nxt[4];
  #pragma unroll
  for (int nt = 0; nt < 4; ++nt) mk_cur[nt] = mask[nt * 16 + l15];
  #pragma unroll
  for (int j = 0; j < 4; ++j)
    gload_lds16(gbase + goff[j], &kv_sh[0][0] + (wave * 4 + j) * 512);
  gbase += gadv;

  unsigned short* const pw = p_sh[wave];
  const int NT = SS / 64;

  for (int t = 0; t < NT; ++t) {
    const int cb = t & 1;
    // prefetch tile t+1 (mask loads FIRST so vmcnt(8) spans exactly mask+stage of t+1)
    if (t + 1 < NT) {
      const int kt1 = (t + 1) * 64;
      #pragma unroll
      for (int nt = 0; nt < 4; ++nt) mk_nxt[nt] = mask[kt1 + nt * 16 + l15];
      #pragma unroll
      for (int j = 0; j < 4; ++j)
        gload_lds16(gbase + goff[j], &kv_sh[cb ^ 1][0] + (wave * 4 + j) * 512);
      gbase += gadv;
      asm volatile("s_waitcnt vmcnt(8)" ::: "memory");
    } else {
      asm volatile("s_waitcnt vmcnt(0)" ::: "memory");
    }
    __builtin_amdgcn_s_barrier();
    asm volatile("" ::: "memory");

    const unsigned short* kb = &kv_sh[cb][0];
    const unsigned short* vb = &kv_sh[cb][4096];

    #pragma unroll
    for (int ksh = 0; ksh < 2; ++ksh) {       // 32-key half
      // QK^T + softmax for the two 16-key groups of this half
      #pragma unroll
      for (int ntk = 0; ntk < 2; ++ntk) {
        const int nt = ksh * 2 + ntk;
        const int ro = (nt * 16 + l15) * 32 + sw8;
        const short8 kf0 = *(const short8*)(kb + ro);
        const short8 kf1 = *(const short8*)(kb + 2048 + ro);
        floatx4 sacc[4];
        #pragma unroll
        for (int mt = 0; mt < 4; ++mt) {
          floatx4 zz = {0.f,0.f,0.f,0.f};
          sacc[mt] = __builtin_amdgcn_mfma_f32_16x16x32_bf16(qf[mt][0], kf0, zz, 0, 0, 0);
          sacc[mt] = __builtin_amdgcn_mfma_f32_16x16x32_bf16(qf[mt][1], kf1, sacc[mt], 0, 0, 0);
        }
        const float mk2 = mk_cur[nt] * L2E;
        #pragma unroll
        for (int mt = 0; mt < 4; ++mt)
          #pragma unroll
          for (int r = 0; r < 4; ++r) {
            const float p = __builtin_amdgcn_exp2f(sacc[mt][r] * SCL2 + mk2);
            lad[mt][r] += p;
            pw[(mt * 16 + lq * 4 + r) * 40 + ntk * 16 + l15] = f2bf_fast(p);
          }
      }
      // PV for this key half (P half fully written by this wave; per-wave LDS, in-order)
      short8 pf[4];
      #pragma unroll
      for (int mt = 0; mt < 4; ++mt)
        pf[mt] = *(const short8*)(pw + (mt * 16 + l15) * 40 + lq * 8);
      #pragma unroll
      for (int ntd = 0; ntd < 4; ++ntd) {
        const short8 vf = *(const short8*)(vb + ksh * 2048 + (ntd * 16 + l15) * 32 + sw8);
        #pragma unroll
        for (int mt = 0; mt < 4; ++mt)
          oacc[mt][ntd] = __builtin_amdgcn_mfma_f32_16x16x32_bf16(pf[mt], vf, oacc[mt][ntd], 0, 0, 0);
      }
    }

    asm volatile("" ::: "memory");
    __builtin_amdgcn_s_barrier();   // protect kv buf reuse two tiles later
    asm volatile("" ::: "memory");

    #pragma unroll
    for (int nt = 0; nt < 4; ++nt) mk_cur[nt] = mk_nxt[nt];
  }

  // epilogue: one DPP row-reduction per (mt,r); O row q = mt*16+lq*4+r, col d = nt*16+l15
  #pragma unroll
  for (int mt = 0; mt < 4; ++mt) {
    float inv[4];
    #pragma unroll
    for (int r = 0; r < 4; ++r) inv[r] = 1.f / rowsum16(lad[mt][r]);
    #pragma unroll
    for (int nt = 0; nt < 4; ++nt) {
      #pragma unroll
      for (int r = 0; r < 4; ++r) {
        const int gq = q0 + wave * 64 + mt * 16 + lq * 4 + r;
        const int gd = h * 64 + nt * 16 + l15;
        O[(size_t)(b * SS + gq) * 768 + gd] = f2bf(oacc[mt][nt][r] * inv[r]);
      }
    }
  }
}

// ---------------------------------------------------------------- layernorm (one block per row, both streams)
struct LnArgs { const float* src[2]; const float* g[2]; const float* bta[2]; float* out[2]; };

__global__ __launch_bounds__(256)
void ln_kernel(LnArgs a) {
  const int z = blockIdx.y;
  const int row = blockIdx.x;
  const int tid = threadIdx.x;
  const float* x = a.src[z] + (size_t)row * 768;
  const float* g = a.g[z];
  const float* bta = a.bta[z];
  const float v0 = x[tid], v1 = x[tid + 256], v2 = x[tid + 512];
  float sum = v0 + v1 + v2;
  float sq  = v0 * v0 + v1 * v1 + v2 * v2;
  #pragma unroll
  for (int d = 1; d < 64; d <<= 1) {
    sum += __shfl_xor(sum, d, 64);
    sq  += __shfl_xor(sq, d, 64);
  }
  __shared__ float ssum[4], ssq[4];
  const int wave = tid >> 6, lane = tid & 63;
  if (lane == 0) { ssum[wave] = sum; ssq[wave] = sq; }
  __syncthreads();
  sum = ssum[0] + ssum[1] + ssum[2] + ssum[3];
  sq  = ssq[0] + ssq[1] + ssq[2] + ssq[3];
  const float mean = sum * (1.f / 768.f);
  const float var  = sq * (1.f / 768.f) - mean * mean;
  const float rs   = rsqrtf(var + 1e-12f);
  float* o = a.out[z] + (size_t)row * 768;
  o[tid]       = (v0 - mean) * rs * g[tid]       + bta[tid];
  o[tid + 256] = (v1 - mean) * rs * g[tid + 256] + bta[tid + 256];
  o[tid + 512] = (v2 - mean) * rs * g[tid + 512] + bta[tid + 512];
}

// ---------------------------------------------------------------- launch
extern "C" void kernel_launch(void* const* d_in, const int* in_sizes, int n_in,
                              void* d_out, int out_size, void* d_ws, size_t ws_size,
                              hipStream_t stream) {
  const float* x1    = (const float*)d_in[0];
  const float* mask1 = (const float*)d_in[1];
  const float* x2    = (const float*)d_in[2];
  const float* mask2 = (const float*)d_in[3];

  char* ws = (char*)d_ws;
  const size_t SZ_X = (size_t)MR * HID_ * 2;     // bf16 [8192,768] = 12,582,912 B
  const size_t SZ_W = (size_t)HID_ * HID_ * 2;   // bf16 [768,768]

  unsigned short* xb0 = (unsigned short*)(ws);
  unsigned short* xb1 = (unsigned short*)(ws + SZ_X);
  unsigned short* wtb[8];
  for (int i = 0; i < 8; ++i) wtb[i] = (unsigned short*)(ws + 2 * SZ_X + i * SZ_W);
  char* qbase = ws + 2 * SZ_X + 8 * SZ_W;
  unsigned short* qkvb[6];
  for (int i = 0; i < 6; ++i) qkvb[i] = (unsigned short*)(qbase + i * SZ_X);
  unsigned short* ctxb[2];
  ctxb[0] = (unsigned short*)(qbase + 6 * SZ_X);
  ctxb[1] = (unsigned short*)(qbase + 7 * SZ_X);
  // proj fp32 buffers alias qkv[0..3] (dead after attention)
  float* projb[2];
  projb[0] = (float*)(qbase);
  projb[1] = (float*)(qbase + 2 * SZ_X);

  // 1. cast inputs to bf16 (both streams, one launch)
  CastArgs ca;
  ca.src[0] = x1; ca.src[1] = x2; ca.dst[0] = xb0; ca.dst[1] = xb1;
  cast_kernel<<<dim3(XELEMS / 1024, 2), 256, 0, stream>>>(ca);

  // 2. transpose+cast weights (q1,k1,v1,q2,k2,v2,d1,d2 at d_in[4+2z])
  WArgs wa;
  for (int z = 0; z < 8; ++z) { wa.src[z] = (const float*)d_in[4 + 2 * z]; wa.dst[z] = wtb[z]; }
  wcast_kernel<<<dim3(24, 24, 8), 256, 0, stream>>>(wa);

  // 3. QKV projections (6 GEMMs batched in grid.z); V outputs written transposed
  GemmArgs ga = {};
  for (int z = 0; z < 6; ++z) {
    ga.A[z]    = (z < 3) ? xb0 : xb1;
    ga.Bt[z]   = wtb[z];
    ga.bias[z] = (const float*)d_in[5 + 2 * z];
    ga.outb[z] = qkvb[z];
    ga.tmode[z] = (z == 2 || z == 5) ? 2 : 0;
  }
  gemm_kernel<0><<<dim3(64, 6, 6), 256, 0, stream>>>(ga);

  // 4. bidirectional cross attention (Q-tile 256, 64 q/wave)
  AttnArgs aa;
  aa.q[0] = qkvb[0]; aa.q[1] = qkvb[3];
  aa.k[0] = qkvb[1]; aa.k[1] = qkvb[4];
  aa.vt[0] = qkvb[2]; aa.vt[1] = qkvb[5];
  aa.mask[0] = mask1; aa.mask[1] = mask2;
  aa.ctx[0] = ctxb[0]; aa.ctx[1] = ctxb[1];
  attn_kernel<<<dim3(8, 12, 8), 256, 0, stream>>>(aa);

  // 5. output projection + bias + residual (fp32 to workspace)
  GemmArgs gp = {};
  for (int w = 0; w < 2; ++w) {
    gp.A[w]     = ctxb[w];
    gp.Bt[w]    = wtb[6 + w];
    gp.bias[w]  = (const float*)d_in[17 + 2 * w];
    gp.resid[w] = (w == 0) ? x1 : x2;
    gp.outf[w]  = projb[w];
  }
  gemm_kernel<1><<<dim3(64, 6, 2), 256, 0, stream>>>(gp);

  // 6. layernorm -> d_out (h1 then h2, one launch)
  float* out = (float*)d_out;
  LnArgs la;
  la.src[0] = projb[0]; la.src[1] = projb[1];
  la.g[0] = (const float*)d_in[20]; la.bta[0] = (const float*)d_in[21];
  la.g[1] = (const float*)d_in[22]; la.bta[1] = (const float*)d_in[23];
  la.out[0] = out; la.out[1] = out + XELEMS;
  ln_kernel<<<dim3(MR, 2), 256, 0, stream>>>(la);
}

// Round 5
// 467.398 us; speedup vs baseline: 1.6148x; 1.6148x over previous
//
#include <hip/hip_runtime.h>
#include <hip/hip_bf16.h>

// Problem constants
#define BB   4
#define SS   2048
#define HID_ 768
#define NH   12
#define HD_  64
#define MR   8192          // B*S
#define XELEMS 6291456     // 8192*768

typedef __attribute__((ext_vector_type(8))) short short8;
typedef __attribute__((ext_vector_type(4))) float floatx4;

__device__ __forceinline__ unsigned short f2bf(float f) {
  union { float f; unsigned int u; } x; x.f = f;
  unsigned int r = x.u + 0x7fffu + ((x.u >> 16) & 1u);  // RNE
  return (unsigned short)(r >> 16);
}

// round-half-up f32 -> bf16 (1 int add + shift; fine vs 0.106 tolerance)
__device__ __forceinline__ unsigned short f2bf_fast(float f) {
  return (unsigned short)((__builtin_bit_cast(unsigned int, f) + 0x8000u) >> 16);
}

// 16-lane (DPP row) rotate-reduce sum — VALU pipe, no LDS traffic
template <int CTRL>
__device__ __forceinline__ float dpp_ror(float x) {
  return __builtin_bit_cast(float, __builtin_amdgcn_update_dpp(
      0, __builtin_bit_cast(int, x), CTRL, 0xF, 0xF, true));
}
__device__ __forceinline__ float rowsum16(float x) {
  x += dpp_ror<0x128>(x);  // row_ror:8
  x += dpp_ror<0x124>(x);  // row_ror:4
  x += dpp_ror<0x122>(x);  // row_ror:2
  x += dpp_ror<0x121>(x);  // row_ror:1
  return x;
}

// async global -> LDS, 16 B per lane; lds base is wave-uniform, HW adds lane*16
__device__ __forceinline__ void gload_lds16(const unsigned short* g, unsigned short* l) {
  __builtin_amdgcn_global_load_lds(
      (const __attribute__((address_space(1))) unsigned int*)g,
      (__attribute__((address_space(3))) unsigned int*)l, 16, 0, 0);
}

// ---------------------------------------------------------------- cast fp32 -> bf16 (both streams)
struct CastArgs { const float* src[2]; unsigned short* dst[2]; };

__global__ __launch_bounds__(256)
void cast_kernel(CastArgs a) {
  const int z = blockIdx.y;
  int i = (blockIdx.x * 256 + threadIdx.x) * 4;
  float4 v = *(const float4*)(a.src[z] + i);
  ushort4 o;
  o.x = f2bf(v.x); o.y = f2bf(v.y); o.z = f2bf(v.z); o.w = f2bf(v.w);
  *(ushort4*)(a.dst[z] + i) = o;
}

// ---------------------------------------------------------------- weight transpose+cast
// in: W[k][n] fp32 (768x768), out: Wt[n][k] bf16
struct WArgs { const float* src[8]; unsigned short* dst[8]; };

__global__ __launch_bounds__(256)
void wcast_kernel(WArgs args) {
  __shared__ float tile[32][33];
  const int w = blockIdx.z;
  const float* __restrict__ src = args.src[w];
  unsigned short* __restrict__ dst = args.dst[w];
  const int n0 = blockIdx.x * 32, k0 = blockIdx.y * 32;
  const int tx = threadIdx.x & 31, ty = threadIdx.x >> 5;  // 32 x 8
  #pragma unroll
  for (int i = 0; i < 4; ++i)
    tile[ty + 8 * i][tx] = src[(size_t)(k0 + ty + 8 * i) * HID_ + n0 + tx];
  __syncthreads();
  #pragma unroll
  for (int i = 0; i < 4; ++i)
    dst[(size_t)(n0 + ty + 8 * i) * HID_ + k0 + tx] = f2bf(tile[tx][ty + 8 * i]);
}

// ---------------------------------------------------------------- GEMM: C = A[M,768] * Bt[N,768]^T
// (round-3 proven form) 128x128 tile, 4 waves of 64x64, 16x16x32 bf16 MFMA,
// BK=32, global_load_lds width-16 staging into unpadded pitch-32 LDS.
// MODE 0: bf16 out; per-z tmode 0 = row-major [tok][hid], 2 = V-transposed [b,h,d,s]
// MODE 1: fp32 out = acc + bias + resid
struct GemmArgs {
  const unsigned short* A[6];
  const unsigned short* Bt[6];
  const float* bias[6];
  const float* resid[6];
  unsigned short* outb[6];
  float* outf[6];
  int tmode[6];
};

template <int MODE>
__global__ __launch_bounds__(256)
void gemm_kernel(GemmArgs args) {
  const int z = blockIdx.z;
  const unsigned short* __restrict__ A  = args.A[z];
  const unsigned short* __restrict__ Bt = args.Bt[z];
  const int m0 = blockIdx.x * 128;
  const int n0 = blockIdx.y * 128;

  __shared__ __align__(16) unsigned short a_sh[128 * 32];  // 8 KB, pitch 32
  __shared__ __align__(16) unsigned short b_sh[128 * 32];

  const int tid  = threadIdx.x;
  const int lane = tid & 63;
  const int wave = tid >> 6;
  const int wm = (wave & 1) * 64;
  const int wn = (wave >> 1) * 64;
  const int l15 = lane & 15;
  const int ko  = lane >> 4;     // 0..3

  floatx4 acc[4][4];
  #pragma unroll
  for (int mt = 0; mt < 4; ++mt)
    #pragma unroll
    for (int nt = 0; nt < 4; ++nt) {
      floatx4 zz = {0.f, 0.f, 0.f, 0.f};
      acc[mt][nt] = zz;
    }

  // staging: 8 chunks of 16 rows x 32 cols; wave handles chunks {2w, 2w+1}
  const int ch0 = wave * 2;
  size_t aoff[2], boff[2];
  unsigned short *adst[2], *bdst[2];
  #pragma unroll
  for (int j = 0; j < 2; ++j) {
    const int ch = ch0 + j;
    const int row = ch * 16 + (lane >> 2);
    const int col = (lane & 3) * 8;
    aoff[j] = (size_t)(m0 + row) * 768 + col;
    boff[j] = (size_t)(n0 + row) * 768 + col;
    adst[j] = a_sh + ch * 512 + lane * 8;
    bdst[j] = b_sh + ch * 512 + lane * 8;
  }

  for (int k0 = 0; k0 < 768; k0 += 32) {
    #pragma unroll
    for (int j = 0; j < 2; ++j) {
      gload_lds16(A  + aoff[j] + k0, adst[j]);
      gload_lds16(Bt + boff[j] + k0, bdst[j]);
    }
    __syncthreads();
    short8 af[4], bfr[4];
    #pragma unroll
    for (int t = 0; t < 4; ++t) {
      af[t]  = *(const short8*)(a_sh + (wm + t * 16 + l15) * 32 + ko * 8);
      bfr[t] = *(const short8*)(b_sh + (wn + t * 16 + l15) * 32 + ko * 8);
    }
    #pragma unroll
    for (int mt = 0; mt < 4; ++mt)
      #pragma unroll
      for (int nt = 0; nt < 4; ++nt)
        acc[mt][nt] = __builtin_amdgcn_mfma_f32_16x16x32_bf16(af[mt], bfr[nt], acc[mt][nt], 0, 0, 0);
    __syncthreads();
  }

  // epilogue. C/D layout: row = (lane>>4)*4 + r, col = lane&15
  if (MODE == 0) {
    const float* __restrict__ bias = args.bias[z];
    unsigned short* __restrict__ out = args.outb[z];
    if (args.tmode[z] == 0) {
      #pragma unroll
      for (int mt = 0; mt < 4; ++mt) {
        const int gm = m0 + wm + mt * 16 + ko * 4;
        #pragma unroll
        for (int nt = 0; nt < 4; ++nt) {
          const int gn = n0 + wn + nt * 16 + l15;
          const float bv = bias[gn];
          #pragma unroll
          for (int r = 0; r < 4; ++r)
            out[(size_t)(gm + r) * 768 + gn] = f2bf(acc[mt][nt][r] + bv);
        }
      }
    } else {
      // V: write transposed [b][h][d][s]; r walks consecutive s -> ushort4 stores
      #pragma unroll
      for (int mt = 0; mt < 4; ++mt) {
        const int gm = m0 + wm + mt * 16 + ko * 4;
        const int bb_ = gm >> 11;
        const int s   = gm & 2047;
        #pragma unroll
        for (int nt = 0; nt < 4; ++nt) {
          const int gn = n0 + wn + nt * 16 + l15;
          const float bv = bias[gn];
          const int h = gn >> 6, d = gn & 63;
          ushort4 o4;
          o4.x = f2bf(acc[mt][nt][0] + bv);
          o4.y = f2bf(acc[mt][nt][1] + bv);
          o4.z = f2bf(acc[mt][nt][2] + bv);
          o4.w = f2bf(acc[mt][nt][3] + bv);
          *(ushort4*)(out + ((size_t)((bb_ * 12 + h) * 64 + d)) * 2048 + s) = o4;
        }
      }
    }
  } else {
    const float* __restrict__ bias  = args.bias[z];
    const float* __restrict__ resid = args.resid[z];
    float* __restrict__ out = args.outf[z];
    #pragma unroll
    for (int mt = 0; mt < 4; ++mt) {
      const int gm = m0 + wm + mt * 16 + ko * 4;
      #pragma unroll
      for (int nt = 0; nt < 4; ++nt) {
        const int gn = n0 + wn + nt * 16 + l15;
        const float bv = bias[gn];
        #pragma unroll
        for (int r = 0; r < 4; ++r)
          out[(size_t)(gm + r) * 768 + gn] = acc[mt][nt][r] + bv + resid[(size_t)(gm + r) * 768 + gn];
      }
    }
  }
}

// ---------------------------------------------------------------- flash attention
// grid: (S/256, H, B*2).  z = b*2 + w; ctx[w] uses Q from the OTHER stream.
// 64 q-rows PER WAVE (block Q-tile 256): every wave must read the whole K/V
// tile from LDS regardless of q-rows, so more q/wave halves LDS-read per unit
// work.  launch_bounds(256,2): cap 256 VGPR — the (256,3) cap of r4 forced
// ~1 GB of scratch spills.  K-tile 64 in 32-key halves (P scratch pitch 40).
// Double-buffered K/V staging via global_load_lds (XOR-swizzled), fine vmcnt.
// No max-tracking; per-row exp sums in registers, one DPP reduce at the end.
struct AttnArgs {
  const unsigned short* q[2];
  const unsigned short* k[2];
  const unsigned short* vt[2];
  const float* mask[2];
  unsigned short* ctx[2];
};

__global__ __launch_bounds__(256, 2)
void attn_kernel(AttnArgs args) {
  const int z = blockIdx.z;
  const int b = z >> 1, w = z & 1;
  const int h = blockIdx.y;
  const int q0 = blockIdx.x * 256;

  const unsigned short* __restrict__ Q  = args.q[1 - w];  // ctx1 <- q2, ctx2 <- q1
  const unsigned short* __restrict__ K  = args.k[w];
  const unsigned short* __restrict__ Vt = args.vt[w] + ((size_t)(b * 12 + h)) * 64 * 2048;
  const float* __restrict__ mask = args.mask[w] + (size_t)b * SS;
  unsigned short* __restrict__ O = args.ctx[w];

  // per buf 8192 elems: K half-tiles [ks][64 key][32 d] at 0,
  // V half-tiles [ksh][64 d][32 key] at 4096. 8-elem blocks XOR-swizzled by row&3.
  __shared__ __align__(16) unsigned short kv_sh[2][8192];
  __shared__ __align__(16) unsigned short p_sh[4][64 * 40];  // 64 q x 32 keys (half), pitch 40

  const int tid  = threadIdx.x;
  const int lane = tid & 63;
  const int wave = tid >> 6;
  const int l15 = lane & 15;
  const int lq  = lane >> 4;   // 0..3
  const int sw8 = (lq ^ (l15 & 3)) * 8;  // swizzled block offset for frag reads

  // staging sources: waves 0,1 stage the two K d-halves; waves 2,3 the two V key-halves
  const unsigned short* gbase;
  int gadv;
  int goff[4];
  {
    const int rl = lane >> 2;                  // row_local 0..15
    const int jb = (lane & 3) ^ (rl & 3);      // swizzled 8-elem block
    if (wave < 2) {
      gbase = K + (size_t)(b * SS) * 768 + h * 64 + (wave & 1) * 32;
      gadv  = 64 * 768;
      #pragma unroll
      for (int j = 0; j < 4; ++j) goff[j] = (j * 16 + rl) * 768 + jb * 8;
    } else {
      gbase = Vt + (wave & 1) * 32;
      gadv  = 64;
      #pragma unroll
      for (int j = 0; j < 4; ++j) goff[j] = (j * 16 + rl) * 2048 + jb * 8;
    }
  }

  // Q fragments: rows q0 + wave*64 + mt*16 + l15, k = ks*32 + lq*8 + j
  short8 qf[4][2];
  #pragma unroll
  for (int mt = 0; mt < 4; ++mt) {
    const size_t qrow = (size_t)(b * SS + q0 + wave * 64 + mt * 16 + l15) * 768 + h * 64;
    qf[mt][0] = *(const short8*)(Q + qrow + lq * 8);
    qf[mt][1] = *(const short8*)(Q + qrow + 32 + lq * 8);
  }

  floatx4 oacc[4][4];
  #pragma unroll
  for (int mt = 0; mt < 4; ++mt)
    #pragma unroll
    for (int nt = 0; nt < 4; ++nt) { floatx4 zz = {0.f,0.f,0.f,0.f}; oacc[mt][nt] = zz; }
  floatx4 lad[4];
  #pragma unroll
  for (int mt = 0; mt < 4; ++mt) { floatx4 zz = {0.f,0.f,0.f,0.f}; lad[mt] = zz; }

  const float SCL2 = 0.125f * 1.4426950408889634f;  // /sqrt(64) * log2(e)
  const float L2E  = 1.4426950408889634f;

  // prefetch tile 0: mask then K/V
  float mk_cur[4], mk_nxt[4];
  #pragma unroll
  for (int nt = 0; nt < 4; ++nt) mk_cur[nt] = mask[nt * 16 + l15];
  #pragma unroll
  for (int j = 0; j < 4; ++j)
    gload_lds16(gbase + goff[j], &kv_sh[0][0] + (wave * 4 + j) * 512);
  gbase += gadv;

  unsigned short* const pw = p_sh[wave];
  const int NT = SS / 64;

  for (int t = 0; t < NT; ++t) {
    const int cb = t & 1;
    // prefetch tile t+1 (mask loads FIRST so vmcnt(8) spans exactly mask+stage of t+1)
    if (t + 1 < NT) {
      const int kt1 = (t + 1) * 64;
      #pragma unroll
      for (int nt = 0; nt < 4; ++nt) mk_nxt[nt] = mask[kt1 + nt * 16 + l15];
      #pragma unroll
      for (int j = 0; j < 4; ++j)
        gload_lds16(gbase + goff[j], &kv_sh[cb ^ 1][0] + (wave * 4 + j) * 512);
      gbase += gadv;
      asm volatile("s_waitcnt vmcnt(8)" ::: "memory");
    } else {
      asm volatile("s_waitcnt vmcnt(0)" ::: "memory");
    }
    __builtin_amdgcn_s_barrier();
    asm volatile("" ::: "memory");

    const unsigned short* kb = &kv_sh[cb][0];
    const unsigned short* vb = &kv_sh[cb][4096];

    #pragma unroll
    for (int ksh = 0; ksh < 2; ++ksh) {       // 32-key half
      // QK^T + softmax for the two 16-key groups of this half
      #pragma unroll
      for (int ntk = 0; ntk < 2; ++ntk) {
        const int nt = ksh * 2 + ntk;
        const int ro = (nt * 16 + l15) * 32 + sw8;
        const short8 kf0 = *(const short8*)(kb + ro);
        const short8 kf1 = *(const short8*)(kb + 2048 + ro);
        const float mk2 = mk_cur[nt] * L2E;
        #pragma unroll
        for (int mt = 0; mt < 4; ++mt) {
          floatx4 zz = {0.f,0.f,0.f,0.f};
          floatx4 sacc = __builtin_amdgcn_mfma_f32_16x16x32_bf16(qf[mt][0], kf0, zz, 0, 0, 0);
          sacc = __builtin_amdgcn_mfma_f32_16x16x32_bf16(qf[mt][1], kf1, sacc, 0, 0, 0);
          ushort4 p4;
          float p0 = __builtin_amdgcn_exp2f(sacc[0] * SCL2 + mk2);
          float p1 = __builtin_amdgcn_exp2f(sacc[1] * SCL2 + mk2);
          float p2 = __builtin_amdgcn_exp2f(sacc[2] * SCL2 + mk2);
          float p3 = __builtin_amdgcn_exp2f(sacc[3] * SCL2 + mk2);
          lad[mt][0] += p0; lad[mt][1] += p1; lad[mt][2] += p2; lad[mt][3] += p3;
          p4.x = f2bf_fast(p0); p4.y = f2bf_fast(p1); p4.z = f2bf_fast(p2); p4.w = f2bf_fast(p3);
          // row = mt*16 + lq*4 + r, col = ntk*16 + l15 — scalar stores (pitch 40)
          pw[(mt * 16 + lq * 4 + 0) * 40 + ntk * 16 + l15] = p4.x;
          pw[(mt * 16 + lq * 4 + 1) * 40 + ntk * 16 + l15] = p4.y;
          pw[(mt * 16 + lq * 4 + 2) * 40 + ntk * 16 + l15] = p4.z;
          pw[(mt * 16 + lq * 4 + 3) * 40 + ntk * 16 + l15] = p4.w;
        }
      }
      // PV for this key half (P half fully written by this wave; per-wave LDS, in-order)
      short8 vf[4];
      #pragma unroll
      for (int ntd = 0; ntd < 4; ++ntd)
        vf[ntd] = *(const short8*)(vb + ksh * 2048 + (ntd * 16 + l15) * 32 + sw8);
      #pragma unroll
      for (int mt = 0; mt < 4; ++mt) {
        const short8 pf = *(const short8*)(pw + (mt * 16 + l15) * 40 + lq * 8);
        #pragma unroll
        for (int ntd = 0; ntd < 4; ++ntd)
          oacc[mt][ntd] = __builtin_amdgcn_mfma_f32_16x16x32_bf16(pf, vf[ntd], oacc[mt][ntd], 0, 0, 0);
      }
    }

    asm volatile("" ::: "memory");
    __builtin_amdgcn_s_barrier();   // protect kv buf reuse two tiles later
    asm volatile("" ::: "memory");

    #pragma unroll
    for (int nt = 0; nt < 4; ++nt) mk_cur[nt] = mk_nxt[nt];
  }

  // epilogue: one DPP row-reduction per (mt,r); O row q = mt*16+lq*4+r, col d = nt*16+l15
  #pragma unroll
  for (int mt = 0; mt < 4; ++mt) {
    float inv[4];
    #pragma unroll
    for (int r = 0; r < 4; ++r) inv[r] = 1.f / rowsum16(lad[mt][r]);
    #pragma unroll
    for (int nt = 0; nt < 4; ++nt) {
      #pragma unroll
      for (int r = 0; r < 4; ++r) {
        const int gq = q0 + wave * 64 + mt * 16 + lq * 4 + r;
        const int gd = h * 64 + nt * 16 + l15;
        O[(size_t)(b * SS + gq) * 768 + gd] = f2bf(oacc[mt][nt][r] * inv[r]);
      }
    }
  }
}

// ---------------------------------------------------------------- layernorm (one block per row, both streams)
struct LnArgs { const float* src[2]; const float* g[2]; const float* bta[2]; float* out[2]; };

__global__ __launch_bounds__(256)
void ln_kernel(LnArgs a) {
  const int z = blockIdx.y;
  const int row = blockIdx.x;
  const int tid = threadIdx.x;
  const float* x = a.src[z] + (size_t)row * 768;
  const float* g = a.g[z];
  const float* bta = a.bta[z];
  const float v0 = x[tid], v1 = x[tid + 256], v2 = x[tid + 512];
  float sum = v0 + v1 + v2;
  float sq  = v0 * v0 + v1 * v1 + v2 * v2;
  #pragma unroll
  for (int d = 1; d < 64; d <<= 1) {
    sum += __shfl_xor(sum, d, 64);
    sq  += __shfl_xor(sq, d, 64);
  }
  __shared__ float ssum[4], ssq[4];
  const int wave = tid >> 6, lane = tid & 63;
  if (lane == 0) { ssum[wave] = sum; ssq[wave] = sq; }
  __syncthreads();
  sum = ssum[0] + ssum[1] + ssum[2] + ssum[3];
  sq  = ssq[0] + ssq[1] + ssq[2] + ssq[3];
  const float mean = sum * (1.f / 768.f);
  const float var  = sq * (1.f / 768.f) - mean * mean;
  const float rs   = rsqrtf(var + 1e-12f);
  float* o = a.out[z] + (size_t)row * 768;
  o[tid]       = (v0 - mean) * rs * g[tid]       + bta[tid];
  o[tid + 256] = (v1 - mean) * rs * g[tid + 256] + bta[tid + 256];
  o[tid + 512] = (v2 - mean) * rs * g[tid + 512] + bta[tid + 512];
}

// ---------------------------------------------------------------- launch
extern "C" void kernel_launch(void* const* d_in, const int* in_sizes, int n_in,
                              void* d_out, int out_size, void* d_ws, size_t ws_size,
                              hipStream_t stream) {
  const float* x1    = (const float*)d_in[0];
  const float* mask1 = (const float*)d_in[1];
  const float* x2    = (const float*)d_in[2];
  const float* mask2 = (const float*)d_in[3];

  char* ws = (char*)d_ws;
  const size_t SZ_X = (size_t)MR * HID_ * 2;     // bf16 [8192,768] = 12,582,912 B
  const size_t SZ_W = (size_t)HID_ * HID_ * 2;   // bf16 [768,768]

  unsigned short* xb0 = (unsigned short*)(ws);
  unsigned short* xb1 = (unsigned short*)(ws + SZ_X);
  unsigned short* wtb[8];
  for (int i = 0; i < 8; ++i) wtb[i] = (unsigned short*)(ws + 2 * SZ_X + i * SZ_W);
  char* qbase = ws + 2 * SZ_X + 8 * SZ_W;
  unsigned short* qkvb[6];
  for (int i = 0; i < 6; ++i) qkvb[i] = (unsigned short*)(qbase + i * SZ_X);
  unsigned short* ctxb[2];
  ctxb[0] = (unsigned short*)(qbase + 6 * SZ_X);
  ctxb[1] = (unsigned short*)(qbase + 7 * SZ_X);
  // proj fp32 buffers alias qkv[0..3] (dead after attention)
  float* projb[2];
  projb[0] = (float*)(qbase);
  projb[1] = (float*)(qbase + 2 * SZ_X);

  // 1. cast inputs to bf16 (both streams, one launch)
  CastArgs ca;
  ca.src[0] = x1; ca.src[1] = x2; ca.dst[0] = xb0; ca.dst[1] = xb1;
  cast_kernel<<<dim3(XELEMS / 1024, 2), 256, 0, stream>>>(ca);

  // 2. transpose+cast weights (q1,k1,v1,q2,k2,v2,d1,d2 at d_in[4+2z])
  WArgs wa;
  for (int z = 0; z < 8; ++z) { wa.src[z] = (const float*)d_in[4 + 2 * z]; wa.dst[z] = wtb[z]; }
  wcast_kernel<<<dim3(24, 24, 8), 256, 0, stream>>>(wa);

  // 3. QKV projections (6 GEMMs batched in grid.z); V outputs written transposed
  GemmArgs ga = {};
  for (int z = 0; z < 6; ++z) {
    ga.A[z]    = (z < 3) ? xb0 : xb1;
    ga.Bt[z]   = wtb[z];
    ga.bias[z] = (const float*)d_in[5 + 2 * z];
    ga.outb[z] = qkvb[z];
    ga.tmode[z] = (z == 2 || z == 5) ? 2 : 0;
  }
  gemm_kernel<0><<<dim3(64, 6, 6), 256, 0, stream>>>(ga);

  // 4. bidirectional cross attention (Q-tile 256, 64 q/wave)
  AttnArgs aa;
  aa.q[0] = qkvb[0]; aa.q[1] = qkvb[3];
  aa.k[0] = qkvb[1]; aa.k[1] = qkvb[4];
  aa.vt[0] = qkvb[2]; aa.vt[1] = qkvb[5];
  aa.mask[0] = mask1; aa.mask[1] = mask2;
  aa.ctx[0] = ctxb[0]; aa.ctx[1] = ctxb[1];
  attn_kernel<<<dim3(8, 12, 8), 256, 0, stream>>>(aa);

  // 5. output projection + bias + residual (fp32 to workspace)
  GemmArgs gp = {};
  for (int w = 0; w < 2; ++w) {
    gp.A[w]     = ctxb[w];
    gp.Bt[w]    = wtb[6 + w];
    gp.bias[w]  = (const float*)d_in[17 + 2 * w];
    gp.resid[w] = (w == 0) ? x1 : x2;
    gp.outf[w]  = projb[w];
  }
  gemm_kernel<1><<<dim3(64, 6, 2), 256, 0, stream>>>(gp);

  // 6. layernorm -> d_out (h1 then h2, one launch)
  float* out = (float*)d_out;
  LnArgs la;
  la.src[0] = projb[0]; la.src[1] = projb[1];
  la.g[0] = (const float*)d_in[20]; la.bta[0] = (const float*)d_in[21];
  la.g[1] = (const float*)d_in[22]; la.bta[1] = (const float*)d_in[23];
  la.out[0] = out; la.out[1] = out + XELEMS;
  ln_kernel<<<dim3(MR, 2), 256, 0, stream>>>(la);
}